// Round 1
// baseline (615.510 us; speedup 1.0000x reference)
//
#include <hip/hip_runtime.h>

#define NCH    64
#define NPTS   16384
#define NS     16
#define NB     4
#define QSCALE 0.125f

// One wave (64 lanes) handles 64 consecutive points n; lane = n within tile.
// Total waves = B*N/64 = 1024 -> grid 256 blocks x 256 threads.
__global__ __launch_bounds__(256) void pt_attn_kernel(
    const float* __restrict__ xyz,     // [B,3,N]
    const float* __restrict__ nxyz,    // [B,3,N,S]
    const float* __restrict__ point,   // [B,C,N]
    const float* __restrict__ cost,    // [B,C,N,S]
    const float* __restrict__ w_k,     // [C,C]
    const float* __restrict__ w_v,     // [C,C]
    const float* __restrict__ w_pos,   // [C,4]
    const float* __restrict__ b_pos,   // [C]
    float* __restrict__ out)           // [B,C,N]
{
    const int wave = (blockIdx.x * blockDim.x + threadIdx.x) >> 6;
    const int lane = threadIdx.x & 63;
    const int tilesPerB = NPTS / 64;          // 256
    const int b = wave / tilesPerB;           // 0..3
    const int n = (wave % tilesPerB) * 64 + lane;

    const float* point_b = point + b * NCH * NPTS;
    const float* cost_b  = cost  + (size_t)b * NCH * NPTS * NS;
    const float* xyz_b   = xyz   + b * 3 * NPTS;
    const float* nxyz_b  = nxyz  + b * 3 * NPTS * NS;

    // ---- Phase A: q'[c] = sum_o w_k[o][c] * point[b,o,n] * SCALE ----
    // w_k indices are wave-uniform -> scalar (s_load) operands.
    float qp[NCH];
#pragma unroll
    for (int c = 0; c < NCH; ++c) qp[c] = 0.f;
    for (int o = 0; o < NCH; ++o) {
        float qo = point_b[o * NPTS + n] * QSCALE;   // coalesced across lanes
#pragma unroll
        for (int c = 0; c < NCH; ++c)
            qp[c] = fmaf(w_k[o * NCH + c], qo, qp[c]);
    }

    // ---- qpos = W_pos^T q' (4-vec), qb = q' . b_pos ----
    float qs0 = 0.f, qs1 = 0.f, qs2 = 0.f, qs3 = 0.f, qb = 0.f;
#pragma unroll
    for (int c = 0; c < NCH; ++c) {
        qs0 = fmaf(qp[c], w_pos[c * 4 + 0], qs0);
        qs1 = fmaf(qp[c], w_pos[c * 4 + 1], qs1);
        qs2 = fmaf(qp[c], w_pos[c * 4 + 2], qs2);
        qs3 = fmaf(qp[c], w_pos[c * 4 + 3], qs3);
        qb  = fmaf(qp[c], b_pos[c], qb);
    }

    // ---- Geometry part of logits: qs.(tmp,norm) + qb ----
    float lg[NS];
    {
        float x0 = xyz_b[0 * NPTS + n];
        float x1 = xyz_b[1 * NPTS + n];
        float x2 = xyz_b[2 * NPTS + n];
        const float4* g0 = (const float4*)(nxyz_b + (0 * NPTS + n) * NS);
        const float4* g1 = (const float4*)(nxyz_b + (1 * NPTS + n) * NS);
        const float4* g2 = (const float4*)(nxyz_b + (2 * NPTS + n) * NS);
#pragma unroll
        for (int s4 = 0; s4 < 4; ++s4) {
            float4 a0 = g0[s4], a1 = g1[s4], a2 = g2[s4];
            float t0, t1, t2, nr;
            t0 = x0 - a0.x; t1 = x1 - a1.x; t2 = x2 - a2.x;
            nr = sqrtf(t0 * t0 + t1 * t1 + t2 * t2);
            lg[s4 * 4 + 0] = fmaf(qs0, t0, fmaf(qs1, t1, fmaf(qs2, t2, fmaf(qs3, nr, qb))));
            t0 = x0 - a0.y; t1 = x1 - a1.y; t2 = x2 - a2.y;
            nr = sqrtf(t0 * t0 + t1 * t1 + t2 * t2);
            lg[s4 * 4 + 1] = fmaf(qs0, t0, fmaf(qs1, t1, fmaf(qs2, t2, fmaf(qs3, nr, qb))));
            t0 = x0 - a0.z; t1 = x1 - a1.z; t2 = x2 - a2.z;
            nr = sqrtf(t0 * t0 + t1 * t1 + t2 * t2);
            lg[s4 * 4 + 2] = fmaf(qs0, t0, fmaf(qs1, t1, fmaf(qs2, t2, fmaf(qs3, nr, qb))));
            t0 = x0 - a0.w; t1 = x1 - a1.w; t2 = x2 - a2.w;
            nr = sqrtf(t0 * t0 + t1 * t1 + t2 * t2);
            lg[s4 * 4 + 3] = fmaf(qs0, t0, fmaf(qs1, t1, fmaf(qs2, t2, fmaf(qs3, nr, qb))));
        }
    }

    // ---- Logits: lg[s] += sum_c q'[c] * cost[b,c,n,s]  (cost pass 1) ----
    // Full unroll: qp[c] must stay a static register index.
#pragma unroll
    for (int c = 0; c < NCH; ++c) {
        const float4* cp = (const float4*)(cost_b + (c * NPTS + n) * NS);
        float4 v0 = cp[0], v1 = cp[1], v2 = cp[2], v3 = cp[3];
        float qc = qp[c];
        lg[0]  = fmaf(qc, v0.x, lg[0]);  lg[1]  = fmaf(qc, v0.y, lg[1]);
        lg[2]  = fmaf(qc, v0.z, lg[2]);  lg[3]  = fmaf(qc, v0.w, lg[3]);
        lg[4]  = fmaf(qc, v1.x, lg[4]);  lg[5]  = fmaf(qc, v1.y, lg[5]);
        lg[6]  = fmaf(qc, v1.z, lg[6]);  lg[7]  = fmaf(qc, v1.w, lg[7]);
        lg[8]  = fmaf(qc, v2.x, lg[8]);  lg[9]  = fmaf(qc, v2.y, lg[9]);
        lg[10] = fmaf(qc, v2.z, lg[10]); lg[11] = fmaf(qc, v2.w, lg[11]);
        lg[12] = fmaf(qc, v3.x, lg[12]); lg[13] = fmaf(qc, v3.y, lg[13]);
        lg[14] = fmaf(qc, v3.z, lg[14]); lg[15] = fmaf(qc, v3.w, lg[15]);
    }

    // ---- Softmax over s ----
    float m = lg[0];
#pragma unroll
    for (int s = 1; s < NS; ++s) m = fmaxf(m, lg[s]);
    float at[NS];
    float Z = 0.f;
#pragma unroll
    for (int s = 0; s < NS; ++s) { at[s] = __expf(lg[s] - m); Z += at[s]; }
    float rz = 1.f / Z;
#pragma unroll
    for (int s = 0; s < NS; ++s) at[s] *= rz;

    // ---- wc[c] = sum_s attn[s] * cost[b,c,n,s]  (cost pass 2) ----
    float wc[NCH];
#pragma unroll
    for (int c = 0; c < NCH; ++c) {
        const float4* cp = (const float4*)(cost_b + (c * NPTS + n) * NS);
        float4 v0 = cp[0], v1 = cp[1], v2 = cp[2], v3 = cp[3];
        float a;
        a = at[0] * v0.x;
        a = fmaf(at[1],  v0.y, a); a = fmaf(at[2],  v0.z, a); a = fmaf(at[3],  v0.w, a);
        a = fmaf(at[4],  v1.x, a); a = fmaf(at[5],  v1.y, a); a = fmaf(at[6],  v1.z, a);
        a = fmaf(at[7],  v1.w, a); a = fmaf(at[8],  v2.x, a); a = fmaf(at[9],  v2.y, a);
        a = fmaf(at[10], v2.z, a); a = fmaf(at[11], v2.w, a); a = fmaf(at[12], v3.x, a);
        a = fmaf(at[13], v3.y, a); a = fmaf(at[14], v3.z, a); a = fmaf(at[15], v3.w, a);
        wc[c] = a;
    }

    // ---- out[b,o,n] = sum_c w_v[o][c] * wc[c] ----
    // w_v rows contiguous -> s_load_dwordx16 batches; stores coalesced across lanes.
    float* out_b = out + b * NCH * NPTS;
    for (int o = 0; o < NCH; ++o) {
        const float* wvr = w_v + o * NCH;
        float acc = 0.f;
#pragma unroll
        for (int c = 0; c < NCH; ++c)
            acc = fmaf(wvr[c], wc[c], acc);
        out_b[o * NPTS + n] = acc;
    }
}

extern "C" void kernel_launch(void* const* d_in, const int* in_sizes, int n_in,
                              void* d_out, int out_size, void* d_ws, size_t ws_size,
                              hipStream_t stream) {
    const float* xyz   = (const float*)d_in[0];
    const float* nxyz  = (const float*)d_in[1];
    const float* point = (const float*)d_in[2];
    // d_in[3] = neighbor_points: unused by the reference computation
    const float* cost  = (const float*)d_in[4];
    const float* w_k   = (const float*)d_in[5];
    const float* w_v   = (const float*)d_in[6];
    const float* w_pos = (const float*)d_in[7];
    const float* b_pos = (const float*)d_in[8];
    float* outp = (float*)d_out;

    dim3 grid(256), block(256);
    hipLaunchKernelGGL(pt_attn_kernel, grid, block, 0, stream,
                       xyz, nxyz, point, cost, w_k, w_v, w_pos, b_pos, outp);
}

// Round 2
// 570.619 us; speedup vs baseline: 1.0787x; 1.0787x over previous
//
#include <hip/hip_runtime.h>

#define NCH    64
#define NPTS   16384
#define NS     16
#define QSCALE 0.125f

// Workgroup-cooperative: block = 256 threads handles 64 consecutive points of
// one batch. Big per-point vectors (qp[64], wc[64]) live in LDS, shared by the
// 4 threads that split each point's S=16 dimension -> tiny per-thread register
// state (acc[16] max), no spills.
// Grid = B*N/64 = 1024 blocks; LDS = 33.25 KB -> 4 blocks/CU, fully co-resident.
__global__ __launch_bounds__(256) void pt_attn_kernel(
    const float* __restrict__ xyz,     // [B,3,N]
    const float* __restrict__ nxyz,    // [B,3,N,S]
    const float* __restrict__ point,   // [B,C,N]
    const float* __restrict__ cost,    // [B,C,N,S]
    const float* __restrict__ w_k,     // [C,C]
    const float* __restrict__ w_v,     // [C,C]
    const float* __restrict__ w_pos,   // [C,4]
    const float* __restrict__ b_pos,   // [C]
    float* __restrict__ out)           // [B,C,N]
{
    __shared__ float ptwc[NCH][64];   // phase 1: scaled point tile; phase 4+: wc[c][n]
    __shared__ float qp[NCH][64];     // qp[c][n] = (W_k^T q)[c] for point n
    __shared__ float qg[5][64];       // per-n: W_pos^T qp (4) and b_pos . qp (1)

    const int t  = threadIdx.x;
    const int b  = blockIdx.x >> 8;          // 256 blocks per batch
    const int n0 = (blockIdx.x & 255) << 6;  // tile base point

    const float* point_b = point + (size_t)b * NCH * NPTS;
    const float* cost_b  = cost  + (size_t)b * NCH * NPTS * NS;
    const float* xyz_b   = xyz   + (size_t)b * 3 * NPTS;
    const float* nxyz_b  = nxyz  + (size_t)b * 3 * NPTS * NS;
    float*       out_b   = out   + (size_t)b * NCH * NPTS;

    // ---- Step 1a: stage scaled point tile [64 o][64 n] (coalesced) ----
#pragma unroll
    for (int i = 0; i < 16; ++i) {
        int flat = t + i * 256;              // 0..4095
        int o = flat >> 6, n = flat & 63;
        ((float*)ptwc)[flat] = point_b[o * NPTS + n0 + n] * QSCALE;
    }
    __syncthreads();

    // ---- Step 1b: qp[c][n] = sum_o w_k[o][c] * ptq[o][n]; wave w does 16 c's ----
    {
        const int w = t >> 6, lane = t & 63;
        const int cbase = w * 16;
        float acc[16];
#pragma unroll
        for (int j = 0; j < 16; ++j) acc[j] = 0.f;
#pragma unroll 4
        for (int o = 0; o < NCH; ++o) {
            float pv = ptwc[o][lane];                 // stride-1 across lanes
            const float* wkr = w_k + o * NCH + cbase; // wave-uniform -> s_load x16
#pragma unroll
            for (int j = 0; j < 16; ++j)
                acc[j] = fmaf(wkr[j], pv, acc[j]);
        }
#pragma unroll
        for (int j = 0; j < 16; ++j)
            qp[cbase + j][lane] = acc[j];
    }
    __syncthreads();

    // ---- Step 1c: qg[j][n] = sum_c qp[c][n]*w_pos[c][j]; qg[4][n] = qp . b_pos ----
    {
        const int n = t & 63, j = t >> 6;    // j = 0..3 (wave-uniform)
        float a = 0.f, ab = 0.f;
#pragma unroll 8
        for (int c = 0; c < NCH; ++c) {
            float q = qp[c][n];
            a = fmaf(q, w_pos[c * 4 + j], a);
            if (j == 0) ab = fmaf(q, b_pos[c], ab);
        }
        qg[j][n] = a;
        if (j == 0) qg[4][n] = ab;
    }
    __syncthreads();

    // ---- Step 2: logits. Thread = (n-local, s-quad). ----
    const int s4 = t & 3, nl = t >> 2;       // nl 0..63
    const int n  = n0 + nl;
    const float4* costp = (const float4*)(cost_b + (size_t)n * NS) + s4;

    float4 lg;
    {
        float x0 = xyz_b[0 * NPTS + n];
        float x1 = xyz_b[1 * NPTS + n];
        float x2 = xyz_b[2 * NPTS + n];
        float4 a0 = *(const float4*)(nxyz_b + (size_t)(0 * NPTS + n) * NS + s4 * 4);
        float4 a1 = *(const float4*)(nxyz_b + (size_t)(1 * NPTS + n) * NS + s4 * 4);
        float4 a2 = *(const float4*)(nxyz_b + (size_t)(2 * NPTS + n) * NS + s4 * 4);
        float qs0 = qg[0][nl], qs1 = qg[1][nl], qs2 = qg[2][nl];
        float qs3 = qg[3][nl], qb  = qg[4][nl];
        float t0, t1, t2, nr;
        t0 = x0 - a0.x; t1 = x1 - a1.x; t2 = x2 - a2.x;
        nr = sqrtf(fmaf(t0, t0, fmaf(t1, t1, t2 * t2)));
        lg.x = fmaf(qs0, t0, fmaf(qs1, t1, fmaf(qs2, t2, fmaf(qs3, nr, qb))));
        t0 = x0 - a0.y; t1 = x1 - a1.y; t2 = x2 - a2.y;
        nr = sqrtf(fmaf(t0, t0, fmaf(t1, t1, t2 * t2)));
        lg.y = fmaf(qs0, t0, fmaf(qs1, t1, fmaf(qs2, t2, fmaf(qs3, nr, qb))));
        t0 = x0 - a0.z; t1 = x1 - a1.z; t2 = x2 - a2.z;
        nr = sqrtf(fmaf(t0, t0, fmaf(t1, t1, t2 * t2)));
        lg.z = fmaf(qs0, t0, fmaf(qs1, t1, fmaf(qs2, t2, fmaf(qs3, nr, qb))));
        t0 = x0 - a0.w; t1 = x1 - a1.w; t2 = x2 - a2.w;
        nr = sqrtf(fmaf(t0, t0, fmaf(t1, t1, t2 * t2)));
        lg.w = fmaf(qs0, t0, fmaf(qs1, t1, fmaf(qs2, t2, fmaf(qs3, nr, qb))));
    }

    // cost pass 1: wave reads 4 KB contiguous per c (perfect coalescing)
#pragma unroll 8
    for (int c = 0; c < NCH; ++c) {
        float4 cv = costp[(size_t)c * NPTS * 4];
        float qc = qp[c][nl];                // 4-lane broadcast, conflict-free
        lg.x = fmaf(qc, cv.x, lg.x);
        lg.y = fmaf(qc, cv.y, lg.y);
        lg.z = fmaf(qc, cv.z, lg.z);
        lg.w = fmaf(qc, cv.w, lg.w);
    }

    // ---- Step 3: softmax over S=16 (4 elems here x 4 lanes) ----
    float m = fmaxf(fmaxf(lg.x, lg.y), fmaxf(lg.z, lg.w));
    m = fmaxf(m, __shfl_xor(m, 1));
    m = fmaxf(m, __shfl_xor(m, 2));
    float4 at;
    at.x = __expf(lg.x - m);
    at.y = __expf(lg.y - m);
    at.z = __expf(lg.z - m);
    at.w = __expf(lg.w - m);
    float Z = at.x + at.y + at.z + at.w;
    Z += __shfl_xor(Z, 1);
    Z += __shfl_xor(Z, 2);
    float rz = 1.f / Z;
    at.x *= rz; at.y *= rz; at.z *= rz; at.w *= rz;

    // ---- Step 4: wc[c][n] = sum_s at[s]*cost[c,n,s] (cost pass 2, from L2/L3) ----
    // ptwc safe to overwrite: last read was before the barrier after step 1b.
#pragma unroll 8
    for (int c = 0; c < NCH; ++c) {
        float4 cv = costp[(size_t)c * NPTS * 4];
        float p = fmaf(at.x, cv.x, fmaf(at.y, cv.y, fmaf(at.z, cv.z, at.w * cv.w)));
        p += __shfl_xor(p, 1);
        p += __shfl_xor(p, 2);
        if (s4 == 0) ptwc[c][nl] = p;
    }
    __syncthreads();

    // ---- Step 5: out[o,n] = sum_c w_v[o][c]*wc[c][n]; wave w does 16 o's ----
    {
        const int w = t >> 6, lane = t & 63;
        const int obase = w * 16;
        float acc[16];
#pragma unroll
        for (int j = 0; j < 16; ++j) acc[j] = 0.f;
#pragma unroll 4
        for (int c = 0; c < NCH; ++c) {
            float wv = ptwc[c][lane];        // stride-1 across lanes
#pragma unroll
            for (int j = 0; j < 16; ++j)
                acc[j] = fmaf(w_v[(obase + j) * NCH + c], wv, acc[j]);  // s_load
        }
#pragma unroll
        for (int j = 0; j < 16; ++j)
            out_b[(obase + j) * NPTS + n0 + lane] = acc[j];  // coalesced
    }
}

extern "C" void kernel_launch(void* const* d_in, const int* in_sizes, int n_in,
                              void* d_out, int out_size, void* d_ws, size_t ws_size,
                              hipStream_t stream) {
    const float* xyz   = (const float*)d_in[0];
    const float* nxyz  = (const float*)d_in[1];
    const float* point = (const float*)d_in[2];
    // d_in[3] = neighbor_points: unused by the reference computation
    const float* cost  = (const float*)d_in[4];
    const float* w_k   = (const float*)d_in[5];
    const float* w_v   = (const float*)d_in[6];
    const float* w_pos = (const float*)d_in[7];
    const float* b_pos = (const float*)d_in[8];
    float* outp = (float*)d_out;

    dim3 grid(1024), block(256);
    hipLaunchKernelGGL(pt_attn_kernel, grid, block, 0, stream,
                       xyz, nxyz, point, cost, w_k, w_v, w_pos, b_pos, outp);
}

// Round 3
// 534.739 us; speedup vs baseline: 1.1510x; 1.0671x over previous
//
#include <hip/hip_runtime.h>

#define NCH    64
#define NPTS   16384
#define NS     16
#define QSCALE 0.125f

// Workgroup-cooperative: block = 256 threads handles 64 consecutive points of
// one batch. Per-point vectors (qp[64], wc[64]) live in LDS. Weight matrices
// are accessed with readfirstlane-forced uniform addresses -> s_load scalar
// ops (R2's divergent broadcast loads cost ~2048 VMEM insts/thread).
// Grid = B*N/64 = 1024 blocks; LDS = 33.25 KB -> 4 blocks/CU.
__global__ __launch_bounds__(256) void pt_attn_kernel(
    const float* __restrict__ xyz,     // [B,3,N]
    const float* __restrict__ nxyz,    // [B,3,N,S]
    const float* __restrict__ point,   // [B,C,N]
    const float* __restrict__ cost,    // [B,C,N,S]
    const float* __restrict__ w_k,     // [C,C]
    const float* __restrict__ w_v,     // [C,C]
    const float* __restrict__ w_pos,   // [C,4]
    const float* __restrict__ b_pos,   // [C]
    float* __restrict__ out)           // [B,C,N]
{
    __shared__ float ptwc[NCH][64];   // phase 1: scaled point tile; phase 4+: wc[c][n]
    __shared__ float qp[NCH][64];     // qp[c][n] = (W_k^T q)[c] for point n
    __shared__ float qg[5][64];       // per-n: W_pos^T qp (4) and b_pos . qp (1)

    const int t  = threadIdx.x;
    const int b  = blockIdx.x >> 8;          // 256 blocks per batch
    const int n0 = (blockIdx.x & 255) << 6;  // tile base point

    const float* point_b = point + (size_t)b * NCH * NPTS;
    const float* cost_b  = cost  + (size_t)b * NCH * NPTS * NS;
    const float* xyz_b   = xyz   + (size_t)b * 3 * NPTS;
    const float* nxyz_b  = nxyz  + (size_t)b * 3 * NPTS * NS;
    float*       out_b   = out   + (size_t)b * NCH * NPTS;

    // Wave index, forced into an SGPR so weight addresses are provably
    // wave-uniform -> s_load instead of per-lane broadcast vector loads.
    const int wu   = __builtin_amdgcn_readfirstlane(t >> 6);
    const int lane = t & 63;

    // ---- Step 1a: stage scaled point tile [64 o][64 n] (coalesced) ----
#pragma unroll
    for (int i = 0; i < 4; ++i) {
        int o = wu * 4 + i;                  // wave-uniform row
        ptwc[o][lane] = point_b[o * NPTS + n0 + lane] * QSCALE;
    }
#pragma unroll
    for (int i = 4; i < 16; ++i) {
        int o = wu * 4 + (i & 3) + (i >> 2) * 16;  // remaining rows, still uniform per wave
        // rows 16..63 interleaved across waves: o = wu*4 + j + 16*k
        ptwc[o][lane] = point_b[o * NPTS + n0 + lane] * QSCALE;
    }
    __syncthreads();

    // ---- Step 1b: qp[c][n] = sum_o w_k[o][c] * ptq[o][n]; wave wu does 16 c's ----
    {
        const int cbase = wu * 16;           // uniform (SGPR)
        float acc[16];
#pragma unroll
        for (int j = 0; j < 16; ++j) acc[j] = 0.f;
#pragma unroll 4
        for (int o = 0; o < NCH; ++o) {
            float pv = ptwc[o][lane];                 // stride-1 across lanes
            const float* wkr = w_k + o * NCH + cbase; // uniform -> s_load_dwordx16
#pragma unroll
            for (int j = 0; j < 16; ++j)
                acc[j] = fmaf(wkr[j], pv, acc[j]);
        }
#pragma unroll
        for (int j = 0; j < 16; ++j)
            qp[cbase + j][lane] = acc[j];
    }
    __syncthreads();

    // ---- Step 1c: qg[j][n] = sum_c qp[c][n]*w_pos[c][j]; qg[4][n] = qp . b_pos ----
    {
        const int j = wu;                    // uniform -> w_pos reads are s_load
        float a = 0.f, ab = 0.f;
#pragma unroll 8
        for (int c = 0; c < NCH; ++c) {
            float q = qp[c][lane];
            a = fmaf(q, w_pos[c * 4 + j], a);
            if (j == 0) ab = fmaf(q, b_pos[c], ab);
        }
        qg[j][lane] = a;
        if (j == 0) qg[4][lane] = ab;
    }
    __syncthreads();

    // ---- Step 2: logits. Thread = (n-local, s-quad). ----
    const int s4 = t & 3, nl = t >> 2;       // nl 0..63
    const int n  = n0 + nl;
    const float4* costp = (const float4*)(cost_b + (size_t)n * NS) + s4;

    float4 lg;
    {
        float x0 = xyz_b[0 * NPTS + n];
        float x1 = xyz_b[1 * NPTS + n];
        float x2 = xyz_b[2 * NPTS + n];
        float4 a0 = *(const float4*)(nxyz_b + (size_t)(0 * NPTS + n) * NS + s4 * 4);
        float4 a1 = *(const float4*)(nxyz_b + (size_t)(1 * NPTS + n) * NS + s4 * 4);
        float4 a2 = *(const float4*)(nxyz_b + (size_t)(2 * NPTS + n) * NS + s4 * 4);
        float qs0 = qg[0][nl], qs1 = qg[1][nl], qs2 = qg[2][nl];
        float qs3 = qg[3][nl], qb  = qg[4][nl];
        float t0, t1, t2, nr;
        t0 = x0 - a0.x; t1 = x1 - a1.x; t2 = x2 - a2.x;
        nr = sqrtf(fmaf(t0, t0, fmaf(t1, t1, t2 * t2)));
        lg.x = fmaf(qs0, t0, fmaf(qs1, t1, fmaf(qs2, t2, fmaf(qs3, nr, qb))));
        t0 = x0 - a0.y; t1 = x1 - a1.y; t2 = x2 - a2.y;
        nr = sqrtf(fmaf(t0, t0, fmaf(t1, t1, t2 * t2)));
        lg.y = fmaf(qs0, t0, fmaf(qs1, t1, fmaf(qs2, t2, fmaf(qs3, nr, qb))));
        t0 = x0 - a0.z; t1 = x1 - a1.z; t2 = x2 - a2.z;
        nr = sqrtf(fmaf(t0, t0, fmaf(t1, t1, t2 * t2)));
        lg.z = fmaf(qs0, t0, fmaf(qs1, t1, fmaf(qs2, t2, fmaf(qs3, nr, qb))));
        t0 = x0 - a0.w; t1 = x1 - a1.w; t2 = x2 - a2.w;
        nr = sqrtf(fmaf(t0, t0, fmaf(t1, t1, t2 * t2)));
        lg.w = fmaf(qs0, t0, fmaf(qs1, t1, fmaf(qs2, t2, fmaf(qs3, nr, qb))));
    }

    // cost pass 1: wave reads 1 KB contiguous per c (perfect coalescing)
#pragma unroll 8
    for (int c = 0; c < NCH; ++c) {
        float4 cv = costp[(size_t)c * NPTS * 4];
        float qc = qp[c][nl];                // 4-lane broadcast, conflict-free
        lg.x = fmaf(qc, cv.x, lg.x);
        lg.y = fmaf(qc, cv.y, lg.y);
        lg.z = fmaf(qc, cv.z, lg.z);
        lg.w = fmaf(qc, cv.w, lg.w);
    }

    // ---- Step 3: softmax over S=16 (4 elems here x 4 lanes) ----
    float m = fmaxf(fmaxf(lg.x, lg.y), fmaxf(lg.z, lg.w));
    m = fmaxf(m, __shfl_xor(m, 1));
    m = fmaxf(m, __shfl_xor(m, 2));
    float4 at;
    at.x = __expf(lg.x - m);
    at.y = __expf(lg.y - m);
    at.z = __expf(lg.z - m);
    at.w = __expf(lg.w - m);
    float Z = at.x + at.y + at.z + at.w;
    Z += __shfl_xor(Z, 1);
    Z += __shfl_xor(Z, 2);
    float rz = 1.f / Z;
    at.x *= rz; at.y *= rz; at.z *= rz; at.w *= rz;

    // ---- Step 4: wc[c][n] = sum_s at[s]*cost[c,n,s] (cost pass 2, from L2/L3) ----
    // ptwc safe to overwrite: last read was before the barrier after step 1b.
#pragma unroll 8
    for (int c = 0; c < NCH; ++c) {
        float4 cv = costp[(size_t)c * NPTS * 4];
        float p = fmaf(at.x, cv.x, fmaf(at.y, cv.y, fmaf(at.z, cv.z, at.w * cv.w)));
        p += __shfl_xor(p, 1);
        p += __shfl_xor(p, 2);
        if (s4 == 0) ptwc[c][nl] = p;
    }
    __syncthreads();

    // ---- Step 5: out[o,n] = sum_c w_v[o][c]*wc[c][n]; wave wu does 16 o's ----
    {
        const int obase = wu * 16;           // uniform (SGPR)
        float acc[16];
#pragma unroll
        for (int j = 0; j < 16; ++j) acc[j] = 0.f;
#pragma unroll 4
        for (int c = 0; c < NCH; ++c) {
            float wv = ptwc[c][lane];        // stride-1 across lanes
            const float* wvc = w_v + c;      // w_v[(obase+j)*NCH + c], uniform rows
#pragma unroll
            for (int j = 0; j < 16; ++j)
                acc[j] = fmaf(wvc[(obase + j) * NCH], wv, acc[j]);  // s_load
        }
#pragma unroll
        for (int j = 0; j < 16; ++j)
            out_b[(obase + j) * NPTS + n0 + lane] = acc[j];  // coalesced
    }
}

extern "C" void kernel_launch(void* const* d_in, const int* in_sizes, int n_in,
                              void* d_out, int out_size, void* d_ws, size_t ws_size,
                              hipStream_t stream) {
    const float* xyz   = (const float*)d_in[0];
    const float* nxyz  = (const float*)d_in[1];
    const float* point = (const float*)d_in[2];
    // d_in[3] = neighbor_points: unused by the reference computation
    const float* cost  = (const float*)d_in[4];
    const float* w_k   = (const float*)d_in[5];
    const float* w_v   = (const float*)d_in[6];
    const float* w_pos = (const float*)d_in[7];
    const float* b_pos = (const float*)d_in[8];
    float* outp = (float*)d_out;

    dim3 grid(1024), block(256);
    hipLaunchKernelGGL(pt_attn_kernel, grid, block, 0, stream,
                       xyz, nxyz, point, cost, w_k, w_v, w_pos, b_pos, outp);
}